// Round 5
// baseline (1908.745 us; speedup 1.0000x reference)
//
#include <hip/hip_runtime.h>
#include <math.h>

#define ND  256    // num_data (steps)
#define SEQ 2048
#define NI  256
#define NH  1024
#define NO  256

#define RB   64                 // recur blocks (all co-resident: 1 block/CU)
#define RT   1024               // recur threads (16 waves)
#define HPB  16                 // hidden units per block (NH / RB)
#define NHP  (NH + 1)           // padded LDS row (break 16-way write conflicts)

#define XTB  32                 // t-tile for xproj
#define OTB  8                  // t-tile for outproj

typedef unsigned long long u64;

// relaxed agent-scope atomics: compile to sc0|sc1 ops that bypass/write-through
// L1+L2 to the device coherence point. The 8-byte payload packs
// {tag:32 | float_bits:32}: tag+value are atomically consistent, so a producer
// needs NO ack-wait, NO flag, NO fence — and a consumer's successful poll IS
// the data load.
#define AL64(p)   __hip_atomic_load((p), __ATOMIC_RELAXED, __HIP_MEMORY_SCOPE_AGENT)
#define AS64(p,v) __hip_atomic_store((p), (v), __ATOMIC_RELAXED, __HIP_MEMORY_SCOPE_AGENT)

// ---------------- input projections, t-tiled: X[t][h] = b[h] + x[t,2047,:]@W --
__global__ void xproj(const float* __restrict__ x,
                      const float* __restrict__ Win1, const float* __restrict__ b1,
                      const float* __restrict__ Win2, const float* __restrict__ b2,
                      float* __restrict__ X1, float* __restrict__ X2) {
    const int   layer = blockIdx.z;
    const int   t0    = blockIdx.y * XTB;
    const int   h     = blockIdx.x * 256 + threadIdx.x;
    const float* W = layer ? Win2 : Win1;
    const float* b = layer ? b2   : b1;
    float*       X = layer ? X2   : X1;

    __shared__ float lx[XTB][NI];          // 32 KB: last seq row for 32 t's
    for (int idx = threadIdx.x; idx < XTB * NI; idx += 256) {
        int r = idx >> 8, c = idx & (NI - 1);
        lx[r][c] = x[(size_t)(t0 + r) * SEQ * NI + (size_t)(SEQ - 1) * NI + c];
    }
    __syncthreads();

    float acc[XTB];
    float bias = b[h];
    #pragma unroll
    for (int r = 0; r < XTB; ++r) acc[r] = bias;

    for (int i = 0; i < NI; ++i) {
        float wv = W[i * NH + h];          // coalesced over h, L1/L2-cached
        #pragma unroll
        for (int r = 0; r < XTB; ++r) acc[r] += lx[r][i] * wv;
    }
    #pragma unroll
    for (int r = 0; r < XTB; ++r) X[(t0 + r) * NH + h] = acc[r];
}

// ---------------- sequential recurrence: 64 blocks, weights LDS-resident -----
// Sync = generation-tagged data, wave-chunked polling:
//   producer: lane0 of wave w stores {tag=t+1 | z1[h]} as ONE 8B atomic.
//             Nothing else: no waitcnt drain, no flag, no LDS counter.
//   consumer: wave w polls its own 64-element chunk (1 u64/lane, coalesced
//             512B/issue), wave-uniform reissue via !__any(bad); s_sleep(1)
//             on miss caps reissue rate (storm guard). A matching poll
//             ALREADY holds the value -> stage to LDS, barrier.
// Safety: block publishes t+1 only after its barrier (all waves observed all
// tag-t elements) => tag t+2 overwrites tag-t data only after every block has
// consumed it => polls never miss their expected tag. LDS ping-pong reuse
// distance spans the per-step barrier. rocprof-safe: every pass re-runs the
// full launch incl. the state memset.
__launch_bounds__(RT, 1)
__global__ void recur(const float* __restrict__ Wr1, const float* __restrict__ Wr2,
                      const float* __restrict__ X1,  const float* __restrict__ X2,
                      u64* Z1b, u64* Z2b, float* Z1hist) {
    __shared__ float lW1[HPB][NHP];        // 64 KB (+pad)
    __shared__ float lW2[HPB][NHP];        // 64 KB (+pad)
    __shared__ float sz1[2][NH];           // 8 KB  z1 staging (ping on t&1)
    __shared__ float sz2[2][NH];           // 8 KB  z2 staging (ping on z2 gen)

    const int tid = threadIdx.x;
    const int b   = blockIdx.x;
    const int h0  = b * HPB;

    // one-time weight residency: consecutive tid -> consecutive h (64B chunks)
    for (int idx = tid; idx < HPB * NH; idx += RT) {
        int hw = idx & (HPB - 1);
        int k  = idx >> 4;                 // HPB == 16
        lW1[hw][k] = Wr1[(size_t)k * NH + h0 + hw];
        lW2[hw][k] = Wr2[(size_t)k * NH + h0 + hw];
    }
    __syncthreads();

    const int w = tid >> 6;                // wave 0..15 <-> hidden unit
    const int l = tid & 63;
    const int h = h0 + w;

    for (int t = 0; t < ND; ++t) {
        const bool even   = (t & 1) == 0;
        const int  q      = t >> 1;
        const bool stage2 = (t == 0) || !even;   // z2 gen changes after even steps
        const int  rd2    = (t == 0) ? 0 : (even ? (q & 1) : ((q + 1) & 1));
        const unsigned e2 = (t == 0) ? 0u : (unsigned)(q + 1);

        // cached broadcast loads — issue first, latency overlaps the poll
        float xv1 = X1[t * NH + h];
        float xv2 = even ? X2[t * NH + h] : 0.0f;

        // ---- poll own element until tag matches (value rides along) ----
        const u64* p1 = Z1b + (t & 1) * NH + tid;
        const u64* p2 = Z2b + rd2 * NH + tid;
        u64 v1 = AL64(p1);
        u64 v2 = stage2 ? AL64(p2) : 0;
        for (;;) {
            bool bad = ((unsigned)(v1 >> 32) != (unsigned)t) ||
                       (stage2 && ((unsigned)(v2 >> 32) != e2));
            if (!__any(bad)) break;        // wave-uniform exit & reissue
            __builtin_amdgcn_s_sleep(1);   // cap reissue rate (storm guard)
            v1 = AL64(p1);
            if (stage2) v2 = AL64(p2);
        }
        sz1[t & 1][tid] = __uint_as_float((unsigned)v1);
        if (stage2) sz2[rd2][tid] = __uint_as_float((unsigned)v2);
        __syncthreads();                   // the ONLY barrier per step

        const float* z1c = sz1[t & 1];
        const float* z2c = sz2[rd2];
        float r1 = 0.0f, r2 = 0.0f;
        #pragma unroll
        for (int j = 0; j < 16; ++j) {
            int k = l + 64 * j;            // conflict-free LDS
            r1 += (z1c[k] + z2c[k]) * lW1[w][k];
        }
        if (even) {
            #pragma unroll
            for (int j = 0; j < 16; ++j) {
                int k = l + 64 * j;
                r2 += z2c[k] * lW2[w][k];
            }
        }
        #pragma unroll
        for (int off = 32; off; off >>= 1) {
            r1 += __shfl_xor(r1, off, 64);
            if (even) r2 += __shfl_xor(r2, off, 64);
        }

        // ---- publish: one tagged 8B store per owned value, fire-and-forget --
        if (l == 0) {
            float z1n = tanhf(xv1 + r1);
            Z1hist[t * NH + h] = z1n;      // plain cached store (read post-kernel)
            if (t < ND - 1) {
                u64 o1 = ((u64)(unsigned)(t + 1) << 32) | (u64)__float_as_uint(z1n);
                AS64(Z1b + ((t + 1) & 1) * NH + h, o1);
                if (even) {
                    float z2h = tanhf(xv2 + r2);
                    u64 o2 = ((u64)(unsigned)(q + 1) << 32) | (u64)__float_as_uint(z2h);
                    AS64(Z2b + ((q + 1) & 1) * NH + h, o2);
                }
            }
        }
        // no producer-side sync at all: fall through into step t+1's poll
    }
}

// ---------------- output projection, t-tiled: out[t] = tanh(z1[t]@Wout + b) --
__global__ void outproj(const float* __restrict__ Z1hist,
                        const float* __restrict__ Wout,
                        const float* __restrict__ bout,
                        float* __restrict__ out) {
    const int t0 = blockIdx.x * OTB;
    const int o  = threadIdx.x;

    __shared__ float lz[OTB][NH];          // 32 KB
    for (int idx = threadIdx.x; idx < OTB * NH; idx += 256) {
        int r = idx >> 10, c = idx & (NH - 1);
        lz[r][c] = Z1hist[(t0 + r) * NH + c];
    }
    __syncthreads();

    float acc[OTB];
    float bias = bout[o];
    #pragma unroll
    for (int r = 0; r < OTB; ++r) acc[r] = bias;

    for (int hh = 0; hh < NH; ++hh) {
        float wv = Wout[hh * NO + o];      // coalesced over o
        #pragma unroll
        for (int r = 0; r < OTB; ++r) acc[r] += lz[r][hh] * wv;
    }
    #pragma unroll
    for (int r = 0; r < OTB; ++r) out[(t0 + r) * NO + o] = tanhf(acc[r]);
}

extern "C" void kernel_launch(void* const* d_in, const int* in_sizes, int n_in,
                              void* d_out, int out_size, void* d_ws, size_t ws_size,
                              hipStream_t stream) {
    const float* x     = (const float*)d_in[0];
    const float* Win1  = (const float*)d_in[1];
    const float* b1    = (const float*)d_in[2];
    const float* Wr1   = (const float*)d_in[3];
    const float* Win2  = (const float*)d_in[4];
    const float* b2    = (const float*)d_in[5];
    const float* Wr2   = (const float*)d_in[6];
    const float* Wout  = (const float*)d_in[7];
    const float* bout  = (const float*)d_in[8];
    float* out = (float*)d_out;

    // workspace layout
    u64*   Z1b = (u64*)d_ws;                // 2*NH u64  ping-pong {tag|z1}
    u64*   Z2b = Z1b + 2 * NH;              // 2*NH u64  ping-pong {tag|z2}
    float* Z1h = (float*)(Z2b + 2 * NH);    // ND*NH
    float* X1  = Z1h + ND * NH;             // ND*NH
    float* X2  = X1 + ND * NH;              // ND*NH

    // zero initial state: value 0.0f with tag 0 == "state before step 0"
    hipMemsetAsync(Z1b, 0, 4 * NH * sizeof(u64), stream);

    dim3 xg(NH / 256, ND / XTB, 2);
    xproj<<<xg, 256, 0, stream>>>(x, Win1, b1, Win2, b2, X1, X2);

    recur<<<RB, RT, 0, stream>>>(Wr1, Wr2, X1, X2, Z1b, Z2b, Z1h);

    outproj<<<ND / OTB, NO, 0, stream>>>(Z1h, Wout, bout, out);
}